// Round 11
// baseline (339.969 us; speedup 1.0000x reference)
//
#include <hip/hip_runtime.h>
#include <hip/hip_bf16.h>

// ClusterLoss fused kernel for MI355X (gfx950).  R11: SINGLE KERNEL.
// Cross-round fit showed ~30 us fixed cost per kernel dispatch in the timed
// metric (R7 139 vs main 85 @2 kernels; R10 150 vs main 50 @3 kernels) ->
// fold prep_centers + main + finalize into one launch.
//  Phase 1: each block stages+normalizes its half's 512 centers fp32->fp8
//           into 64 KB swizzled LDS (centers are L3-resident; redundant
//           reads cheap); writes cnorm (redundant identical writes, benign).
//  Phase 2: R10's proven rt loop (BM=64 A-tile, keyed-float argmax, XCD
//           pairing pair=bx&255 half=bx>>8, kbuf plain stores).
//  Phase 3: last-block-done (threadfence/syncthreads/atomicAdd counter);
//           512th block reduces kbuf/nfg/cnorm -> out[0] internally.
// Counter zeroed via capture-safe hipMemsetAsync on stream.
// loss_n = 1 - 2 d na/nf + na^2, keyed low-10-bits = 1023-k.

#define D 128
#define BM 64

typedef __attribute__((ext_vector_type(4))) float floatx4;

template <bool HI>
__device__ __forceinline__ unsigned int pk_fp8(float a, float b, unsigned int old) {
    return (unsigned int)__builtin_amdgcn_cvt_pk_fp8_f32(a, b, (int)old, HI);
}

__device__ __forceinline__ float key_pack(float v, unsigned int inv_k) {
    unsigned int u = __builtin_bit_cast(unsigned int, v);
    unsigned int r = (0x3FFu & inv_k) | (~0x3FFu & u);   // v_bfi_b32
    return __builtin_bit_cast(float, r);
}

__device__ __forceinline__ float sq4(float4 v) {
    return v.x*v.x + v.y*v.y + v.z*v.z + v.w*v.w;
}

__global__ __launch_bounds__(512, 4) void cluster_all(
    const float* __restrict__ feats,        // [N][128] fp32
    const float* __restrict__ centers,      // [1024][128] fp32
    float* __restrict__ kbuf,               // [2][N] keyed floats
    float* __restrict__ nfg,                // [N] row sum-of-squares
    float* __restrict__ cnorm,              // [1024] center norms
    unsigned int* __restrict__ counter,     // zeroed by memset on stream
    float* __restrict__ out,                // [1]
    int N, int rtPer) {

    extern __shared__ unsigned char lds[];
    unsigned char* Bs = lds;                 // 65536 B (512 centers, swizzled)
    unsigned char* As = lds + 512 * D;       // 8192 B (64 rows, swizzled)
    __shared__ float bv[4][BM];              // per-(wn,row) keyed floats
    __shared__ float wsum[8];
    __shared__ int   lastFlag;

    const int tid  = threadIdx.x;            // 0..511, 8 waves
    const int lane = tid & 63;
    const int wave = tid >> 6;
    const int wm   = wave & 1;               // row half of the 64-row tile
    const int wn   = wave >> 1;              // 0..3: 128-center slice
    const int m16  = lane & 15;
    const int quad = lane >> 4;              // 0..3
    const int q1   = quad >> 1, q0 = quad & 1;
    const int m8   = m16 & 7;

    const int pair = blockIdx.x & 255;       // row group; p and p+256 share an XCD
    const int half = blockIdx.x >> 8;        // center half

    // ---- Phase 1: stage + normalize this half's 512 centers -> fp8 LDS ----
    {
        const float* csrc = centers + (size_t)half * 512 * D;
        const int cl = tid & 7;              // 8 threads per center row
        #pragma unroll
        for (int p = 0; p < 8; ++p) {
            const int r = p * 64 + (tid >> 3);       // local center row
            const float* cp = csrc + (size_t)r * D + cl * 16;
            float4 u0 = *(const float4*)(cp);
            float4 u1 = *(const float4*)(cp + 4);
            float4 u2 = *(const float4*)(cp + 8);
            float4 u3 = *(const float4*)(cp + 12);
            float s = sq4(u0) + sq4(u1) + sq4(u2) + sq4(u3);
            s += __shfl_xor(s, 1);
            s += __shfl_xor(s, 2);
            s += __shfl_xor(s, 4);           // full row sumsq in all 8 lanes
            float n   = sqrtf(s);
            float inv = 1.0f / fmaxf(n, 1e-12f);
            unsigned int w0 = pk_fp8<false>(u0.x*inv, u0.y*inv, 0u);
            w0 = pk_fp8<true>(u0.z*inv, u0.w*inv, w0);
            unsigned int w1 = pk_fp8<false>(u1.x*inv, u1.y*inv, 0u);
            w1 = pk_fp8<true>(u1.z*inv, u1.w*inv, w1);
            unsigned int w2 = pk_fp8<false>(u2.x*inv, u2.y*inv, 0u);
            w2 = pk_fp8<true>(u2.z*inv, u2.w*inv, w2);
            unsigned int w3 = pk_fp8<false>(u3.x*inv, u3.y*inv, 0u);
            w3 = pk_fp8<true>(u3.z*inv, u3.w*inv, w3);
            uint4 pack = make_uint4(w0, w1, w2, w3);
            *(uint4*)&Bs[r * D + ((cl ^ (r & 7)) << 4)] = pack;
            if (cl == 0) cnorm[half * 512 + r] = n;  // redundant identical writes
        }
    }

    // ---- Prefetch A for rt=0 ----
    float4 v[4];
    {
        const int row0 = pair * rtPer * BM;
        #pragma unroll
        for (int s = 0; s < 4; ++s) {
            int id = s * 512 + tid;
            int r  = id >> 5;
            int c4 = id & 31;
            v[s] = *(const float4*)(feats + (size_t)(row0 + r) * D + c4 * 4);
        }
    }

    // ---- Phase 2: rt loop (R10 core, unchanged) ----
    for (int rt = 0; rt < rtPer; ++rt) {
        const int row0 = (pair * rtPer + rt) * BM;

        #pragma unroll
        for (int s = 0; s < 4; ++s) {
            int id = s * 512 + tid;
            int r  = id >> 5;
            int c4 = id & 31;
            float4 t = v[s];
            unsigned int w = pk_fp8<false>(t.x, t.y, 0u);
            w = pk_fp8<true>(t.z, t.w, w);
            int pc = (c4 >> 2) ^ (r & 7);
            *(unsigned int*)&As[r * D + pc * 16 + (c4 & 3) * 4] = w;
            if (half == 0) {                 // wave-uniform
                float sq = sq4(t);
                #pragma unroll
                for (int m = 1; m <= 16; m <<= 1) sq += __shfl_xor(sq, m);
                if ((tid & 31) == 0) nfg[row0 + r] = sq;
            }
        }
        __syncthreads();                     // As (and Bs on rt 0) visible

        if (rt + 1 < rtPer) {
            const int nrow0 = row0 + BM;
            #pragma unroll
            for (int s = 0; s < 4; ++s) {
                int id = s * 512 + tid;
                int r  = id >> 5;
                int c4 = id & 31;
                v[s] = *(const float4*)(feats + (size_t)(nrow0 + r) * D + c4 * 4);
            }
        }

        long long afr[2][4];
        #pragma unroll
        for (int i = 0; i < 2; ++i) {
            const int r = wm * 32 + i * 16 + m16;
            #pragma unroll
            for (int kk = 0; kk < 4; ++kk) {
                int pc = (2 * kk + q1) ^ m8;
                afr[i][kk] = *(const long long*)&As[r * D + pc * 16 + q0 * 8];
            }
        }

        float best[8];
        #pragma unroll
        for (int s = 0; s < 8; ++s) best[s] = -3.0e38f;

        #pragma unroll
        for (int ch = 0; ch < 4; ++ch) {
            const int clocal = wn * 128 + ch * 32;
            const int kglob  = half * 512 + clocal + m16;
            const unsigned int inv0 = 1023u - (unsigned)kglob;
            const unsigned int inv1 = inv0 - 16u;
            floatx4 acc[2][2];
            #pragma unroll
            for (int i = 0; i < 2; ++i)
                #pragma unroll
                for (int j = 0; j < 2; ++j)
                    acc[i][j] = (floatx4){0.f, 0.f, 0.f, 0.f};

            #pragma unroll
            for (int kk = 0; kk < 4; ++kk) {
                long long bfr[2];
                #pragma unroll
                for (int j = 0; j < 2; ++j) {
                    int rr = clocal + j * 16 + m16;
                    int pc = (2 * kk + q1) ^ m8;
                    bfr[j] = *(const long long*)&Bs[rr * D + pc * 16 + q0 * 8];
                }
                #pragma unroll
                for (int i = 0; i < 2; ++i)
                    #pragma unroll
                    for (int j = 0; j < 2; ++j)
                        acc[i][j] = __builtin_amdgcn_mfma_f32_16x16x32_fp8_fp8(
                            afr[i][kk], bfr[j], acc[i][j], 0, 0, 0);
            }

            #pragma unroll
            for (int i = 0; i < 2; ++i)
                #pragma unroll
                for (int r = 0; r < 4; ++r) {
                    const int slot = i * 4 + r;
                    float c0 = key_pack(acc[i][0][r], inv0);
                    float c1 = key_pack(acc[i][1][r], inv1);
                    best[slot] = fmaxf(best[slot], fmaxf(c0, c1));
                }
        }

        #pragma unroll
        for (int mask = 1; mask <= 8; mask <<= 1)
            #pragma unroll
            for (int s = 0; s < 8; ++s)
                best[s] = fmaxf(best[s], __shfl_xor(best[s], mask));

        if (m16 == 0) {
            #pragma unroll
            for (int s = 0; s < 8; ++s) {
                int i = s >> 2, rr = s & 3;
                int row = wm * 32 + i * 16 + quad * 4 + rr;
                bv[wn][row] = best[s];
            }
        }
        __syncthreads();

        if (tid < BM) {
            float kmax = fmaxf(fmaxf(bv[0][tid], bv[1][tid]),
                               fmaxf(bv[2][tid], bv[3][tid]));
            kbuf[(size_t)half * N + row0 + tid] = kmax;
        }
    }

    // ---- Phase 3: last-block-done reduction ----
    __threadfence();                         // each thread releases its stores
    __syncthreads();
    if (tid == 0) {
        unsigned int old = atomicAdd(counter, 1u);
        lastFlag = (old == gridDim.x - 1) ? 1 : 0;
    }
    __syncthreads();
    if (lastFlag) {
        __threadfence();                     // acquire side
        const float4* k0  = (const float4*)kbuf;
        const float4* k1  = (const float4*)(kbuf + N);
        const float4* nf4 = (const float4*)nfg;
        float lsum = 0.0f;
        const int iters = N / (4 * 512);     // 64
        for (int it = 0; it < iters; ++it) {
            int i4 = it * 512 + tid;
            float4 a = k0[i4], b = k1[i4], f = nf4[i4];
            #pragma unroll
            for (int c = 0; c < 4; ++c) {
                float ka_ = c == 0 ? a.x : c == 1 ? a.y : c == 2 ? a.z : a.w;
                float kb_ = c == 0 ? b.x : c == 1 ? b.y : c == 2 ? b.z : b.w;
                float ff  = c == 0 ? f.x : c == 1 ? f.y : c == 2 ? f.z : f.w;
                float kmax = fmaxf(ka_, kb_);
                unsigned int u = __builtin_bit_cast(unsigned int, kmax);
                int   ka = 1023 - (int)(u & 1023u);
                float d  = __builtin_bit_cast(float, (u & 0xFFFFFC00u) | 0x200u);
                float nf = fmaxf(sqrtf(ff), 1e-12f);
                float na = cnorm[ka];
                lsum += 1.0f - 2.0f * d * na / nf + na * na;
            }
        }
        #pragma unroll
        for (int m = 1; m <= 32; m <<= 1) lsum += __shfl_xor(lsum, m);
        if (lane == 0) wsum[wave] = lsum;
        __syncthreads();
        if (tid == 0) {
            float total = 0.0f;
            #pragma unroll
            for (int w = 0; w < 8; ++w) total += wsum[w];
            out[0] = total / (float)N;
        }
    }
}

extern "C" void kernel_launch(void* const* d_in, const int* in_sizes, int n_in,
                              void* d_out, int out_size, void* d_ws, size_t ws_size,
                              hipStream_t stream) {
    const float* feats   = (const float*)d_in[0];
    const float* centers = (const float*)d_in[1];
    const int N = in_sizes[0] / D;   // 131072
    const int K = in_sizes[1] / D;   // 1024

    char* ws = (char*)d_ws;
    float*        kbuf    = (float*)ws;                                   // 2N floats
    float*        nfg     = (float*)(ws + (size_t)2 * N * sizeof(float)); // N floats
    float*        cnorm   = (float*)(ws + (size_t)3 * N * sizeof(float)); // K floats
    unsigned int* counter = (unsigned int*)(ws + (size_t)3 * N * sizeof(float)
                                               + (size_t)K * sizeof(float));
    float* out = (float*)d_out;

    (void)hipMemsetAsync(counter, 0, sizeof(unsigned int), stream);

    const int smem = 512 * D + BM * D;   // 73728 B -> 2 blocks/CU with slack
    (void)hipFuncSetAttribute((const void*)cluster_all,
                              hipFuncAttributeMaxDynamicSharedMemorySize, smem);

    const int rtPer = 8;
    const int pairs = N / (rtPer * BM);      // 256
    cluster_all<<<2 * pairs, 512, smem, stream>>>(feats, centers, kbuf, nfg,
                                                  cnorm, counter, out, N, rtPer);
}